// Round 3
// baseline (560.073 us; speedup 1.0000x reference)
//
#include <hip/hip_runtime.h>
#include <stdint.h>

typedef _Float16 half8 __attribute__((ext_vector_type(8)));
typedef float floatx16 __attribute__((ext_vector_type(16)));
typedef unsigned long long u64;

#define ALPHA_ 1.0f
#define BETA_ 0.25f
#define NUM_EMBEDS 8192
#define EMBED_DIM 512
#define B_ 32
#define T_ 256
#define N_TOK 8192

// ---------------- ws layout (bytes) ----------------
// wexact   @ 0        (64 KB)  u64 packed exact min: monokey<<32 | code
// cnorm    @ 65536    (32 KB)  ||c||^2 (fp32 exact)
// counts   @ 98304    (32 KB)
// znorm    @ 131072   (32 KB)  ||z_tok||^2 (fp32)
// sse      @ 163840   (4 B)
// nflag    @ 163844   (4 B)
// maxC2    @ 163848   (4 B)   uint bits of max ||c||^2
// worklist @ 163856   (32 KB)
// cut      @ 196624   (32 KB) f32 per-token rescore cutoff (flagged only)
// slot_m1  @ 1  MB    (8 MB)  u64 [128 chunks][8192 tok] chunk min1 key
// slot_d   @ 9  MB    (2 MB)  f16 [128][8192] (min2 - min1) delta
// cb_h     @ 10 MB    (8 MB)  f16 fragment-major codebook (single plane)
// zt_h     @ 18 MB    (8 MB)  f16 fragment-major -2*z^T (single plane)
// ---------------------------------------------------
// fragment-major (halves):
//   cb_h: [ctile32][slot(32)][lane(64)][8]          ctile stride 16384
//   zt_h: [tb128][slot(32)][q(4)][lane(64)][8]      tb stride 65536
// Single-plane numerics: |err(dot)| <= 2^-9 ||z|| maxC  (f16 RNE on both
// operands + cross terms). Gap test uses THR = 2B + slack; flagged tokens
// are exactly rescored over chunks with chunkmin <= m1 + THR (provably
// sufficient: true-argmin chunk always qualifies).

__device__ __forceinline__ uint32_t mono(float s) {
    uint32_t u = __float_as_uint(s);
    return (u & 0x80000000u) ? ~u : (u | 0x80000000u);
}
__device__ __forceinline__ float unmono(uint32_t v) {
    return __uint_as_float((v & 0x80000000u) ? (v ^ 0x80000000u) : ~v);
}

__global__ void pack_cb_kernel(const float* __restrict__ cb, _Float16* __restrict__ cf,
                               float* __restrict__ cnorm, unsigned int* __restrict__ maxC2) {
    int row = blockIdx.x * 4 + (threadIdx.x >> 6);
    int l = threadIdx.x & 63;
    const float* src = cb + (size_t)row * EMBED_DIM + l * 8;
    float4 v0 = *(const float4*)src;
    float4 v1 = *(const float4*)(src + 4);
    float x[8] = {v0.x, v0.y, v0.z, v0.w, v1.x, v1.y, v1.z, v1.w};
    half8 hh;
    float s = 0.f;
#pragma unroll
    for (int j = 0; j < 8; ++j) {
        s += x[j] * x[j];
        hh[j] = (_Float16)x[j];
    }
    // lane l covers d in [8l, 8l+8): slot = (l>>2)*2 + ((l>>1)&1), half = l&1
    int slot = (l >> 2) * 2 + ((l >> 1) & 1);
    int flane = (row & 31) + (l & 1) * 32;
    *(half8*)(cf + (size_t)(row >> 5) * 16384 + (size_t)slot * 512 + flane * 8) = hh;
#pragma unroll
    for (int d = 32; d; d >>= 1) s += __shfl_xor(s, d, 64);
    if (l == 0) {
        cnorm[row] = s;
        atomicMax(maxC2, __float_as_uint(s));
    }
}

__global__ void pack_z_kernel(const float* __restrict__ z, _Float16* __restrict__ zf,
                              float* __restrict__ znorm) {
    int tid = threadIdx.x;
    int l = tid & 63, ds = tid >> 6;  // ds 0..3 selects d-subgroup
    int n = blockIdx.x * 64 + l;      // global token
    int b = n >> 8, t = n & 255;
    int kk = ds >> 1, hfb = ds & 1;
    int tb = n >> 7, q = (n >> 5) & 3;
    size_t lanebase = (size_t)tb * 65536 + (size_t)q * 512 +
                      (size_t)((n & 31) + hfb * 32) * 8;
    float zz = 0.f;
    for (int g = 0; g < 16; ++g) {
        int d0 = g * 32 + ds * 8;
        const float* src = z + ((size_t)b * EMBED_DIM + d0) * T_ + t;
        half8 hh;
#pragma unroll
        for (int j = 0; j < 8; ++j) {
            float zo = src[(size_t)j * T_];
            zz += zo * zo;
            hh[j] = (_Float16)(-2.0f * zo);
        }
        int slot = g * 2 + kk;
        *(half8*)(zf + lanebase + (size_t)slot * 2048) = hh;
    }
    atomicAdd(&znorm[n], zz);
}

// ---- pass 1: single-plane f16 argmin GEMM, barrier-free, no LDS.
//      4 independent waves/block, each owns 64 codes x 128 tokens.
//      3-deep register prefetch (12 loads in flight/wave) to ride out
//      HBM-class latency seen in R2 (FETCH 80GB vs 32MB working set). ----
#define MFMA16(a, b, c) __builtin_amdgcn_mfma_f32_32x32x16_f16(a, b, c, 0, 0, 0)

#define LDSET(s, hs)                                                  \
    fr[s][0] = *(const half8*)(Ab0 + (hs) * 512 + l8);                \
    fr[s][1] = *(const half8*)(Ab1 + (hs) * 512 + l8);                \
    fr[s][2] = *(const half8*)(Bb + (hs) * 2048 + 0 * 512 + l8);      \
    fr[s][3] = *(const half8*)(Bb + (hs) * 2048 + 1 * 512 + l8);      \
    fr[s][4] = *(const half8*)(Bb + (hs) * 2048 + 2 * 512 + l8);      \
    fr[s][5] = *(const half8*)(Bb + (hs) * 2048 + 3 * 512 + l8);

__global__ __launch_bounds__(256, 2) void argmin_kernel(
    const _Float16* __restrict__ cb_h, const _Float16* __restrict__ zt_h,
    const float* __restrict__ cnorm, u64* __restrict__ slot_m1,
    _Float16* __restrict__ slot_d) {
    const int tid = threadIdx.x;
    const int l = tid & 63;
    const int wv = tid >> 6;  // 0..3
    const int l31 = l & 31;
    const int hf = l >> 5;
    const int cid = blockIdx.y * 4 + wv;  // 64-code chunk id (0..127)
    const _Float16* Ab0 = cb_h + (size_t)(cid * 2) * 16384;
    const _Float16* Ab1 = Ab0 + 16384;
    const _Float16* Bb = zt_h + (size_t)blockIdx.x * 65536;
    const int l8 = l * 8;

    floatx16 acc[2][4];
#pragma unroll
    for (int a = 0; a < 2; ++a)
#pragma unroll
        for (int q = 0; q < 4; ++q)
#pragma unroll
            for (int r = 0; r < 16; ++r) acc[a][q][r] = 0.f;

    half8 fr[3][6];
    LDSET(0, 0)
    LDSET(1, 1)
#pragma unroll
    for (int t = 0; t < 32; ++t) {
        const int s = t % 3;
        if (t + 2 < 32) {
            LDSET((t + 2) % 3, t + 2)
        }
#pragma unroll
        for (int q = 0; q < 4; ++q) acc[0][q] = MFMA16(fr[s][0], fr[s][2 + q], acc[0][q]);
#pragma unroll
        for (int q = 0; q < 4; ++q) acc[1][q] = MFMA16(fr[s][1], fr[s][2 + q], acc[1][q]);
    }

    // epilogue: per (lane,q) one token; this wave covers 64 codes = its chunk
    const int cb0 = cid * 64;
#pragma unroll
    for (int q = 0; q < 4; ++q) {
        u64 m1k = ~0ULL;
        float m1v = 3.4e38f, m2 = 3.4e38f;
#pragma unroll
        for (int ti = 0; ti < 2; ++ti)
#pragma unroll
            for (int g = 0; g < 4; ++g) {
                const int cb4 = cb0 + ti * 32 + g * 8 + hf * 4;
                float4 cn = *(const float4*)(cnorm + cb4);
                float sv[4] = {cn.x + acc[ti][q][g * 4 + 0], cn.y + acc[ti][q][g * 4 + 1],
                               cn.z + acc[ti][q][g * 4 + 2], cn.w + acc[ti][q][g * 4 + 3]};
#pragma unroll
                for (int r = 0; r < 4; ++r) {
                    u64 key = ((u64)mono(sv[r]) << 32) | (uint32_t)(cb4 + r);
                    if (key < m1k) { m2 = m1v; m1v = sv[r]; m1k = key; }
                    else m2 = fminf(m2, sv[r]);
                }
            }
        u64 ok = __shfl_xor(m1k, 32, 64);
        float ov = __shfl_xor(m1v, 32, 64);
        float om2 = __shfl_xor(m2, 32, 64);
        if (ok < m1k) { m2 = fminf(fminf(m2, om2), m1v); m1v = ov; m1k = ok; }
        else m2 = fminf(fminf(m2, om2), ov);
        if (hf == 0) {
            int tok = blockIdx.x * 128 + q * 32 + l31;
            slot_m1[((size_t)cid << 13) + tok] = m1k;
            slot_d[((size_t)cid << 13) + tok] = (_Float16)(m2 - m1v);
        }
    }
}

// ---- combine: merge 128 chunk summaries; deterministic-bound gap test ----
__global__ void combine_kernel(const u64* __restrict__ slot_m1, const _Float16* __restrict__ slot_d,
                               const float* __restrict__ znorm, const unsigned int* __restrict__ maxC2,
                               u64* __restrict__ wexact, int* __restrict__ worklist,
                               int* __restrict__ nflag, float* __restrict__ cut) {
    int tok = blockIdx.x * 256 + threadIdx.x;
    u64 g1 = ~0ULL;
    float g1v = 3.4e38f, g2 = 3.4e38f;
    for (int c = 0; c < 128; ++c) {
        u64 k = slot_m1[((size_t)c << 13) + tok];
        float kv = unmono((uint32_t)(k >> 32));
        float v2 = kv + (float)slot_d[((size_t)c << 13) + tok];
        if (k < g1) { g2 = fminf(g2, g1v); g1 = k; g1v = kv; }
        else g2 = fminf(g2, kv);
        g2 = fminf(g2, v2);
    }
    // deterministic error bound: B = 2^-9 ||z|| maxC ; THR = 2B + slack
    float maxC = sqrtf(__uint_as_float(*maxC2));
    float thr = sqrtf(znorm[tok]) * maxC * (1.0f / 256.0f) + 0.15f;
    if (g2 - g1v > thr) wexact[tok] = g1;
    else {
        int i = atomicAdd(nflag, 1);
        if (i < 8192) worklist[i] = tok;
        cut[tok] = g1v + thr;
    }
}

// ---- fallback: exact fp32 rescore of flagged tokens, chunk-pruned ----
__global__ void fallback_kernel(const float* __restrict__ z, const float* __restrict__ cb,
                                const float* __restrict__ cnorm,
                                const int* __restrict__ worklist, const int* __restrict__ nflag,
                                const u64* __restrict__ slot_m1, const float* __restrict__ cut,
                                u64* __restrict__ wexact) {
    int n = *nflag;
    if (n > 8192) n = 8192;
    const int l = threadIdx.x & 63, wv = threadIdx.x >> 6;
    for (int fi = blockIdx.x; fi < n; fi += gridDim.x) {
        int tok = worklist[fi];
        int b = tok >> 8, t = tok & 255;
        const float* zp = z + ((size_t)b * EMBED_DIM) * T_ + t;
        float zr[8];
#pragma unroll
        for (int j = 0; j < 8; ++j) zr[j] = zp[(size_t)(l * 8 + j) * T_];
        float cutv = cut[tok];
        u64 m1 = ~0ULL;
        for (int cid = wv; cid < 128; cid += 4) {
            u64 sk = slot_m1[((size_t)cid << 13) + tok];
            if (unmono((uint32_t)(sk >> 32)) > cutv) continue;  // chunk cannot hold true argmin
            for (int j = 0; j < 64; ++j) {
                int c = cid * 64 + j;
                const float* cp = cb + (size_t)c * EMBED_DIM + l * 8;
                float4 a = *(const float4*)cp, bb = *(const float4*)(cp + 4);
                float dot = zr[0] * a.x + zr[1] * a.y + zr[2] * a.z + zr[3] * a.w +
                            zr[4] * bb.x + zr[5] * bb.y + zr[6] * bb.z + zr[7] * bb.w;
#pragma unroll
                for (int m = 32; m; m >>= 1) dot += __shfl_xor(dot, m, 64);
                if (l == 0) {
                    float s = cnorm[c] - 2.0f * dot;
                    u64 key = ((u64)mono(s) << 32) | (uint32_t)c;
                    if (key < m1) m1 = key;
                }
            }
        }
        if (l == 0 && m1 != ~0ULL) atomicMin(&wexact[tok], m1);
    }
}

__global__ void gather_kernel(const float* __restrict__ z, const float* __restrict__ cb,
                              const u64* __restrict__ wexact,
                              float* __restrict__ out, int* __restrict__ counts,
                              float* __restrict__ sse_acc) {
    __shared__ unsigned int sIdx[64];
    __shared__ float red[4];
    const int tid = threadIdx.x;
    const int n0 = blockIdx.x * 64;
    const int b = n0 >> 8;
    const int t0 = n0 & 255;
    if (tid < 64) {
        unsigned int idx = (unsigned int)(wexact[n0 + tid] & 0xffffffffULL);
        sIdx[tid] = idx;
        atomicAdd(&counts[idx], 1);
    }
    __syncthreads();
    const int w = tid >> 6;
    const int lane = tid & 63;
    const float* crow = cb + (size_t)sIdx[lane] * EMBED_DIM;
    const size_t base = ((size_t)b * EMBED_DIM) * T_ + (size_t)(t0 + lane);
    float sse = 0.f;
    for (int d = w; d < EMBED_DIM; d += 4) {
        float v = crow[d];
        size_t o = base + (size_t)d * T_;
        float diff = v - z[o];
        out[o] = v;
        sse += diff * diff;
    }
    for (int m = 32; m; m >>= 1) sse += __shfl_xor(sse, m, 64);
    if (lane == 0) red[w] = sse;
    __syncthreads();
    if (tid == 0) atomicAdd(sse_acc, red[0] + red[1] + red[2] + red[3]);
}

__global__ void finalize_kernel(const int* __restrict__ counts,
                                const float* __restrict__ sse_acc,
                                float* __restrict__ out) {
    __shared__ float red[4];
    const int tid = threadIdx.x;
    float e = 0.f;
    for (int k = tid; k < NUM_EMBEDS; k += 256) {
        float p = (float)counts[k] * (1.0f / (float)N_TOK);
        e += p * logf(p + 1e-10f);
    }
    for (int m = 32; m; m >>= 1) e += __shfl_xor(e, m, 64);
    if ((tid & 63) == 0) red[tid >> 6] = e;
    __syncthreads();
    if (tid == 0) {
        float ent = red[0] + red[1] + red[2] + red[3];
        size_t off = (size_t)B_ * EMBED_DIM * T_;
        out[off + 0] = (ALPHA_ * BETA_) * sse_acc[0] / (float)((size_t)N_TOK * EMBED_DIM);
        out[off + 1] = expf(-ent);
    }
}

extern "C" void kernel_launch(void* const* d_in, const int* in_sizes, int n_in,
                              void* d_out, int out_size, void* d_ws, size_t ws_size,
                              hipStream_t stream) {
    const float* z = (const float*)d_in[0];
    const float* cb = (const float*)d_in[1];
    float* out = (float*)d_out;
    char* ws = (char*)d_ws;
    u64* wexact = (u64*)ws;
    float* cnorm = (float*)(ws + 65536);
    int* counts = (int*)(ws + 98304);
    float* znorm = (float*)(ws + 131072);
    float* sse = (float*)(ws + 163840);
    int* nflag = (int*)(ws + 163844);
    unsigned int* maxC2 = (unsigned int*)(ws + 163848);
    int* worklist = (int*)(ws + 163856);
    float* cut = (float*)(ws + 196624);
    u64* slot_m1 = (u64*)(ws + (1ull << 20));
    _Float16* slot_d = (_Float16*)(ws + (9ull << 20));
    _Float16* cb_h = (_Float16*)(ws + (10ull << 20));
    _Float16* zt_h = (_Float16*)(ws + (18ull << 20));

    hipMemsetAsync(wexact, 0xFF, NUM_EMBEDS * sizeof(u64), stream);
    // counts (32K) + znorm (32K) + sse + nflag + maxC2
    hipMemsetAsync(counts, 0, 65536 + 12, stream);

    pack_cb_kernel<<<NUM_EMBEDS / 4, 256, 0, stream>>>(cb, cb_h, cnorm, maxC2);
    pack_z_kernel<<<N_TOK / 64, 256, 0, stream>>>(z, zt_h, znorm);
    argmin_kernel<<<dim3(N_TOK / 128, 32), 256, 0, stream>>>(cb_h, zt_h, cnorm, slot_m1, slot_d);
    combine_kernel<<<N_TOK / 256, 256, 0, stream>>>(slot_m1, slot_d, znorm, maxC2, wexact, worklist, nflag, cut);
    fallback_kernel<<<1024, 256, 0, stream>>>(z, cb, cnorm, worklist, nflag, slot_m1, cut, wexact);
    gather_kernel<<<N_TOK / 64, 256, 0, stream>>>(z, cb, wexact, out, counts, sse);
    finalize_kernel<<<1, 256, 0, stream>>>(counts, sse, out);
}

// Round 4
// 465.704 us; speedup vs baseline: 1.2026x; 1.2026x over previous
//
#include <hip/hip_runtime.h>
#include <stdint.h>

typedef _Float16 half8 __attribute__((ext_vector_type(8)));
typedef float floatx16 __attribute__((ext_vector_type(16)));
typedef unsigned long long u64;

#define ALPHA_ 1.0f
#define BETA_ 0.25f
#define NUM_EMBEDS 8192
#define EMBED_DIM 512
#define B_ 32
#define T_ 256
#define N_TOK 8192
#define MAXPAIRS (1 << 20)

// ---------------- ws layout (bytes) ----------------
// wexact   @ 0        (64 KB)  u64 packed exact min: monokey<<32 | code
// cnorm    @ 65536    (32 KB)  ||c||^2 (fp32 exact)
// counts   @ 98304    (32 KB)
// znorm    @ 131072   (32 KB)  ||z_tok||^2 (fp32)
// sse      @ 163840   (4 B)
// npairs   @ 163844   (4 B)
// maxC2    @ 163848   (4 B)   uint bits of max ||c||^2
// slot_m1  @ 1  MB    (8 MB)  u64 [128 chunks][8192 tok] chunk min1 key
// slot_d   @ 9  MB    (2 MB)  f16 [128][8192] (min2 - min1) delta
// cb_h     @ 10 MB    (8 MB)  f16 fragment-major codebook (single plane)
// zt_h     @ 18 MB    (8 MB)  f16 fragment-major -2*z^T (single plane)
// pairs    @ 26 MB    (4 MB)  int (tok<<7)|cid rescore worklist
// ---------------------------------------------------
// fragment-major (halves):
//   cb_h: [ctile32][slot(32)][lane(64)][8]          ctile stride 16384
//   zt_h: [tb128][slot(32)][q(4)][lane(64)][8]      tb stride 65536
// Single-plane numerics: |err(dot)| <= 2^-9 ||z|| maxC. Gap test THR = 2B +
// slack; flagged tokens exactly rescored over chunks with chunkmin <= g1+THR
// (provably sufficient: the true-argmin chunk always qualifies).

__device__ __forceinline__ uint32_t mono(float s) {
    uint32_t u = __float_as_uint(s);
    return (u & 0x80000000u) ? ~u : (u | 0x80000000u);
}
__device__ __forceinline__ float unmono(uint32_t v) {
    return __uint_as_float((v & 0x80000000u) ? (v ^ 0x80000000u) : ~v);
}

__global__ void pack_cb_kernel(const float* __restrict__ cb, _Float16* __restrict__ cf,
                               float* __restrict__ cnorm, unsigned int* __restrict__ maxC2) {
    int row = blockIdx.x * 4 + (threadIdx.x >> 6);
    int l = threadIdx.x & 63;
    const float* src = cb + (size_t)row * EMBED_DIM + l * 8;
    float4 v0 = *(const float4*)src;
    float4 v1 = *(const float4*)(src + 4);
    float x[8] = {v0.x, v0.y, v0.z, v0.w, v1.x, v1.y, v1.z, v1.w};
    half8 hh;
    float s = 0.f;
#pragma unroll
    for (int j = 0; j < 8; ++j) {
        s += x[j] * x[j];
        hh[j] = (_Float16)x[j];
    }
    // lane l covers d in [8l, 8l+8): slot = (l>>2)*2 + ((l>>1)&1), half = l&1
    int slot = (l >> 2) * 2 + ((l >> 1) & 1);
    int flane = (row & 31) + (l & 1) * 32;
    *(half8*)(cf + (size_t)(row >> 5) * 16384 + (size_t)slot * 512 + flane * 8) = hh;
#pragma unroll
    for (int d = 32; d; d >>= 1) s += __shfl_xor(s, d, 64);
    if (l == 0) {
        cnorm[row] = s;
        atomicMax(maxC2, __float_as_uint(s));
    }
}

__global__ void pack_z_kernel(const float* __restrict__ z, _Float16* __restrict__ zf,
                              float* __restrict__ znorm) {
    int tid = threadIdx.x;
    int l = tid & 63, ds = tid >> 6;  // ds 0..3 selects d-subgroup
    int n = blockIdx.x * 64 + l;      // global token
    int b = n >> 8, t = n & 255;
    int kk = ds >> 1, hfb = ds & 1;
    int tb = n >> 7, q = (n >> 5) & 3;
    size_t lanebase = (size_t)tb * 65536 + (size_t)q * 512 +
                      (size_t)((n & 31) + hfb * 32) * 8;
    float zz = 0.f;
    for (int g = 0; g < 16; ++g) {
        int d0 = g * 32 + ds * 8;
        const float* src = z + ((size_t)b * EMBED_DIM + d0) * T_ + t;
        half8 hh;
#pragma unroll
        for (int j = 0; j < 8; ++j) {
            float zo = src[(size_t)j * T_];
            zz += zo * zo;
            hh[j] = (_Float16)(-2.0f * zo);
        }
        int slot = g * 2 + kk;
        *(half8*)(zf + lanebase + (size_t)slot * 2048) = hh;
    }
    atomicAdd(&znorm[n], zz);
}

// ---- pass 1: single-plane f16 argmin GEMM, barrier-free, no LDS.
//      4 independent waves/block, each owns 64 codes x 128 tokens.
//      3-deep register prefetch (18 loads in flight/wave). ----
#define MFMA16(a, b, c) __builtin_amdgcn_mfma_f32_32x32x16_f16(a, b, c, 0, 0, 0)

#define LDSET(s, hs)                                                  \
    fr[s][0] = *(const half8*)(Ab0 + (hs) * 512 + l8);                \
    fr[s][1] = *(const half8*)(Ab1 + (hs) * 512 + l8);                \
    fr[s][2] = *(const half8*)(Bb + (hs) * 2048 + 0 * 512 + l8);      \
    fr[s][3] = *(const half8*)(Bb + (hs) * 2048 + 1 * 512 + l8);      \
    fr[s][4] = *(const half8*)(Bb + (hs) * 2048 + 2 * 512 + l8);      \
    fr[s][5] = *(const half8*)(Bb + (hs) * 2048 + 3 * 512 + l8);

__global__ __launch_bounds__(256, 2) void argmin_kernel(
    const _Float16* __restrict__ cb_h, const _Float16* __restrict__ zt_h,
    const float* __restrict__ cnorm, u64* __restrict__ slot_m1,
    _Float16* __restrict__ slot_d) {
    const int tid = threadIdx.x;
    const int l = tid & 63;
    const int wv = tid >> 6;  // 0..3
    const int l31 = l & 31;
    const int hf = l >> 5;
    const int cid = blockIdx.y * 4 + wv;  // 64-code chunk id (0..127)
    const _Float16* Ab0 = cb_h + (size_t)(cid * 2) * 16384;
    const _Float16* Ab1 = Ab0 + 16384;
    const _Float16* Bb = zt_h + (size_t)blockIdx.x * 65536;
    const int l8 = l * 8;

    floatx16 acc[2][4];
#pragma unroll
    for (int a = 0; a < 2; ++a)
#pragma unroll
        for (int q = 0; q < 4; ++q)
#pragma unroll
            for (int r = 0; r < 16; ++r) acc[a][q][r] = 0.f;

    half8 fr[3][6];
    LDSET(0, 0)
    LDSET(1, 1)
#pragma unroll
    for (int t = 0; t < 32; ++t) {
        const int s = t % 3;
        if (t + 2 < 32) {
            LDSET((t + 2) % 3, t + 2)
        }
#pragma unroll
        for (int q = 0; q < 4; ++q) acc[0][q] = MFMA16(fr[s][0], fr[s][2 + q], acc[0][q]);
#pragma unroll
        for (int q = 0; q < 4; ++q) acc[1][q] = MFMA16(fr[s][1], fr[s][2 + q], acc[1][q]);
    }

    // epilogue: per (lane,q) one token; this wave covers 64 codes = its chunk
    const int cb0 = cid * 64;
#pragma unroll
    for (int q = 0; q < 4; ++q) {
        u64 m1k = ~0ULL;
        float m1v = 3.4e38f, m2 = 3.4e38f;
#pragma unroll
        for (int ti = 0; ti < 2; ++ti)
#pragma unroll
            for (int g = 0; g < 4; ++g) {
                const int cb4 = cb0 + ti * 32 + g * 8 + hf * 4;
                float4 cn = *(const float4*)(cnorm + cb4);
                float sv[4] = {cn.x + acc[ti][q][g * 4 + 0], cn.y + acc[ti][q][g * 4 + 1],
                               cn.z + acc[ti][q][g * 4 + 2], cn.w + acc[ti][q][g * 4 + 3]};
#pragma unroll
                for (int r = 0; r < 4; ++r) {
                    u64 key = ((u64)mono(sv[r]) << 32) | (uint32_t)(cb4 + r);
                    if (key < m1k) { m2 = m1v; m1v = sv[r]; m1k = key; }
                    else m2 = fminf(m2, sv[r]);
                }
            }
        u64 ok = __shfl_xor(m1k, 32, 64);
        float ov = __shfl_xor(m1v, 32, 64);
        float om2 = __shfl_xor(m2, 32, 64);
        if (ok < m1k) { m2 = fminf(fminf(m2, om2), m1v); m1v = ov; m1k = ok; }
        else m2 = fminf(fminf(m2, om2), ov);
        if (hf == 0) {
            int tok = blockIdx.x * 128 + q * 32 + l31;
            slot_m1[((size_t)cid << 13) + tok] = m1k;
            slot_d[((size_t)cid << 13) + tok] = (_Float16)(m2 - m1v);
        }
    }
}

// ---- combine: 4 threads/token merge 128 chunk summaries; deterministic-bound
//      gap test; emit (tok,chunk) rescore pairs for flagged tokens ----
__global__ void combine_kernel(const u64* __restrict__ slot_m1, const _Float16* __restrict__ slot_d,
                               const float* __restrict__ znorm, const unsigned int* __restrict__ maxC2,
                               u64* __restrict__ wexact, int* __restrict__ pairs,
                               int* __restrict__ npairs) {
    int tid = threadIdx.x;
    int tok = blockIdx.x * 64 + (tid >> 2);
    int sub = tid & 3;
    u64 g1 = ~0ULL;
    float g1v = 3.4e38f, g2 = 3.4e38f;
    for (int c = sub; c < 128; c += 4) {
        u64 k = slot_m1[((size_t)c << 13) + tok];
        float kv = unmono((uint32_t)(k >> 32));
        float v2 = kv + (float)slot_d[((size_t)c << 13) + tok];
        if (k < g1) { g2 = fminf(g2, g1v); g1 = k; g1v = kv; }
        else g2 = fminf(g2, kv);
        g2 = fminf(g2, v2);
    }
    // xor-butterfly merge across the 4 sub-lanes (all lanes get the result)
#pragma unroll
    for (int m = 1; m < 4; m <<= 1) {
        u64 ok = __shfl_xor(g1, m, 64);
        float ov = __shfl_xor(g1v, m, 64);
        float o2 = __shfl_xor(g2, m, 64);
        if (ok < g1) { g2 = fminf(fminf(g2, o2), g1v); g1 = ok; g1v = ov; }
        else g2 = fminf(fminf(g2, o2), ov);
    }
    // deterministic error bound: B = 2^-9 ||z|| maxC ; THR = 2B + slack
    float maxC = sqrtf(__uint_as_float(*maxC2));
    float thr = sqrtf(znorm[tok]) * maxC * (1.0f / 256.0f) + 0.15f;
    if (g2 - g1v > thr) {
        if (sub == 0) wexact[tok] = g1;
    } else {
        float cutv = g1v + thr;
        for (int c = sub; c < 128; c += 4) {
            u64 k = slot_m1[((size_t)c << 13) + tok];
            if (unmono((uint32_t)(k >> 32)) <= cutv) {
                int i = atomicAdd(npairs, 1);
                if (i < MAXPAIRS) pairs[i] = (tok << 7) | c;
            }
        }
    }
}

// ---- fallback v2: exact fp32 rescore, one wave per (tok,chunk) pair,
//      one lane per code; z staged once per pair into a per-wave LDS strip ----
__global__ void fallback_kernel(const float* __restrict__ z, const float* __restrict__ cb,
                                const float* __restrict__ cnorm,
                                const int* __restrict__ pairs, const int* __restrict__ npairs,
                                u64* __restrict__ wexact) {
    __shared__ float zs[4][512];
    int n = *npairs;
    if (n > MAXPAIRS) n = MAXPAIRS;
    const int l = threadIdx.x & 63, wv = threadIdx.x >> 6;
    int wid = blockIdx.x * 4 + wv;
    const int wstride = gridDim.x * 4;
    for (int pi = wid; pi < n; pi += wstride) {
        int pk = pairs[pi];
        int tok = pk >> 7, cid = pk & 127;
        int b = tok >> 8, t = tok & 255;
        const float* zp = z + (size_t)b * EMBED_DIM * T_ + t;
        float zv[8];
#pragma unroll
        for (int j = 0; j < 8; ++j) zv[j] = zp[(size_t)(l * 8 + j) * T_];
        *(float4*)&zs[wv][l * 8] = make_float4(zv[0], zv[1], zv[2], zv[3]);
        *(float4*)&zs[wv][l * 8 + 4] = make_float4(zv[4], zv[5], zv[6], zv[7]);
        // same-wave produce->consume: compiler inserts lgkmcnt wait, no barrier
        int code = cid * 64 + l;
        const float* cp = cb + (size_t)code * EMBED_DIM;
        float acc = 0.f;
#pragma unroll 4
        for (int d = 0; d < 512; d += 4) {
            float4 cv = *(const float4*)(cp + d);
            float4 zq = *(const float4*)&zs[wv][d];
            acc += cv.x * zq.x + cv.y * zq.y + cv.z * zq.z + cv.w * zq.w;
        }
        float s = cnorm[code] - 2.0f * acc;
        u64 key = ((u64)mono(s) << 32) | (uint32_t)code;
#pragma unroll
        for (int m = 32; m; m >>= 1) {
            u64 ok = __shfl_xor(key, m, 64);
            key = ok < key ? ok : key;
        }
        if (l == 0) atomicMin(&wexact[tok], key);
    }
}

__global__ void gather_kernel(const float* __restrict__ z, const float* __restrict__ cb,
                              const u64* __restrict__ wexact,
                              float* __restrict__ out, int* __restrict__ counts,
                              float* __restrict__ sse_acc) {
    __shared__ unsigned int sIdx[64];
    __shared__ float red[4];
    const int tid = threadIdx.x;
    const int n0 = blockIdx.x * 64;
    const int b = n0 >> 8;
    const int t0 = n0 & 255;
    if (tid < 64) {
        unsigned int idx = (unsigned int)(wexact[n0 + tid] & 0xffffffffULL);
        sIdx[tid] = idx;
        atomicAdd(&counts[idx], 1);
    }
    __syncthreads();
    const int w = tid >> 6;
    const int lane = tid & 63;
    const float* crow = cb + (size_t)sIdx[lane] * EMBED_DIM;
    const size_t base = ((size_t)b * EMBED_DIM) * T_ + (size_t)(t0 + lane);
    float sse = 0.f;
    for (int d = w; d < EMBED_DIM; d += 4) {
        float v = crow[d];
        size_t o = base + (size_t)d * T_;
        float diff = v - z[o];
        out[o] = v;
        sse += diff * diff;
    }
    for (int m = 32; m; m >>= 1) sse += __shfl_xor(sse, m, 64);
    if (lane == 0) red[w] = sse;
    __syncthreads();
    if (tid == 0) atomicAdd(sse_acc, red[0] + red[1] + red[2] + red[3]);
}

__global__ void finalize_kernel(const int* __restrict__ counts,
                                const float* __restrict__ sse_acc,
                                float* __restrict__ out) {
    __shared__ float red[4];
    const int tid = threadIdx.x;
    float e = 0.f;
    for (int k = tid; k < NUM_EMBEDS; k += 256) {
        float p = (float)counts[k] * (1.0f / (float)N_TOK);
        e += p * logf(p + 1e-10f);
    }
    for (int m = 32; m; m >>= 1) e += __shfl_xor(e, m, 64);
    if ((tid & 63) == 0) red[tid >> 6] = e;
    __syncthreads();
    if (tid == 0) {
        float ent = red[0] + red[1] + red[2] + red[3];
        size_t off = (size_t)B_ * EMBED_DIM * T_;
        out[off + 0] = (ALPHA_ * BETA_) * sse_acc[0] / (float)((size_t)N_TOK * EMBED_DIM);
        out[off + 1] = expf(-ent);
    }
}

extern "C" void kernel_launch(void* const* d_in, const int* in_sizes, int n_in,
                              void* d_out, int out_size, void* d_ws, size_t ws_size,
                              hipStream_t stream) {
    const float* z = (const float*)d_in[0];
    const float* cb = (const float*)d_in[1];
    float* out = (float*)d_out;
    char* ws = (char*)d_ws;
    u64* wexact = (u64*)ws;
    float* cnorm = (float*)(ws + 65536);
    int* counts = (int*)(ws + 98304);
    float* znorm = (float*)(ws + 131072);
    float* sse = (float*)(ws + 163840);
    int* npairs = (int*)(ws + 163844);
    unsigned int* maxC2 = (unsigned int*)(ws + 163848);
    u64* slot_m1 = (u64*)(ws + (1ull << 20));
    _Float16* slot_d = (_Float16*)(ws + (9ull << 20));
    _Float16* cb_h = (_Float16*)(ws + (10ull << 20));
    _Float16* zt_h = (_Float16*)(ws + (18ull << 20));
    int* pairs = (int*)(ws + (26ull << 20));

    hipMemsetAsync(wexact, 0xFF, NUM_EMBEDS * sizeof(u64), stream);
    // counts (32K) + znorm (32K) + sse + npairs + maxC2
    hipMemsetAsync(counts, 0, 65536 + 12, stream);

    pack_cb_kernel<<<NUM_EMBEDS / 4, 256, 0, stream>>>(cb, cb_h, cnorm, maxC2);
    pack_z_kernel<<<N_TOK / 64, 256, 0, stream>>>(z, zt_h, znorm);
    argmin_kernel<<<dim3(N_TOK / 128, 32), 256, 0, stream>>>(cb_h, zt_h, cnorm, slot_m1, slot_d);
    combine_kernel<<<N_TOK / 64, 256, 0, stream>>>(slot_m1, slot_d, znorm, maxC2, wexact, pairs, npairs);
    fallback_kernel<<<512, 256, 0, stream>>>(z, cb, cnorm, pairs, npairs, wexact);
    gather_kernel<<<N_TOK / 64, 256, 0, stream>>>(z, cb, wexact, out, counts, sse);
    finalize_kernel<<<1, 256, 0, stream>>>(counts, sse, out);
}

// Round 5
// 440.970 us; speedup vs baseline: 1.2701x; 1.0561x over previous
//
#include <hip/hip_runtime.h>
#include <stdint.h>

typedef _Float16 half8 __attribute__((ext_vector_type(8)));
typedef float floatx16 __attribute__((ext_vector_type(16)));
typedef unsigned long long u64;

#define ALPHA_ 1.0f
#define BETA_ 0.25f
#define NUM_EMBEDS 8192
#define EMBED_DIM 512
#define B_ 32
#define T_ 256
#define N_TOK 8192
#define MAXPAIRS (1 << 20)

// ---------------- ws layout (bytes) ----------------
// wexact   @ 0        (64 KB)  u64 packed exact min: monokey<<32 | code
// cnorm    @ 65536    (32 KB)  ||c||^2 (fp32 exact)
// counts   @ 98304    (32 KB)
// znorm    @ 131072   (32 KB)  ||z_tok||^2 (fp32)
// sse      @ 163840   (4 B)
// npairs   @ 163844   (4 B)
// maxC2    @ 163848   (4 B)   uint bits of max ||c||^2
// slot_m1  @ 1  MB    (8 MB)  u64 [128 chunks][8192 tok] chunk min1 key
// slot_d   @ 9  MB    (2 MB)  f16 [128][8192] (min2 - min1) delta
// cb_h     @ 10 MB    (8 MB)  f16 fragment-major codebook (single plane)
// zt_h     @ 18 MB    (8 MB)  f16 fragment-major -2*z^T (single plane)
// pairs    @ 26 MB    (4 MB)  int (tok<<7)|cid rescore worklist
// ---------------------------------------------------
// fragment-major (halves):
//   cb_h: [ctile32][slot(32)][lane(64)][8]          ctile stride 16384
//   zt_h: [tb128][slot(32)][q(4)][lane(64)][8]      tb stride 65536
// Single-plane numerics: |err(dot)| <= 2^-9 ||z|| maxC. Gap test THR = 2B +
// slack; flagged tokens exactly rescored over chunks with chunkmin <= g1+THR
// (provably sufficient: the true-argmin chunk always qualifies).

__device__ __forceinline__ uint32_t mono(float s) {
    uint32_t u = __float_as_uint(s);
    return (u & 0x80000000u) ? ~u : (u | 0x80000000u);
}
__device__ __forceinline__ float unmono(uint32_t v) {
    return __uint_as_float((v & 0x80000000u) ? (v ^ 0x80000000u) : ~v);
}

__global__ void pack_cb_kernel(const float* __restrict__ cb, _Float16* __restrict__ cf,
                               float* __restrict__ cnorm, unsigned int* __restrict__ maxC2) {
    int row = blockIdx.x * 4 + (threadIdx.x >> 6);
    int l = threadIdx.x & 63;
    const float* src = cb + (size_t)row * EMBED_DIM + l * 8;
    float4 v0 = *(const float4*)src;
    float4 v1 = *(const float4*)(src + 4);
    float x[8] = {v0.x, v0.y, v0.z, v0.w, v1.x, v1.y, v1.z, v1.w};
    half8 hh;
    float s = 0.f;
#pragma unroll
    for (int j = 0; j < 8; ++j) {
        s += x[j] * x[j];
        hh[j] = (_Float16)x[j];
    }
    // lane l covers d in [8l, 8l+8): slot = (l>>2)*2 + ((l>>1)&1), half = l&1
    int slot = (l >> 2) * 2 + ((l >> 1) & 1);
    int flane = (row & 31) + (l & 1) * 32;
    *(half8*)(cf + (size_t)(row >> 5) * 16384 + (size_t)slot * 512 + flane * 8) = hh;
#pragma unroll
    for (int d = 32; d; d >>= 1) s += __shfl_xor(s, d, 64);
    if (l == 0) {
        cnorm[row] = s;
        atomicMax(maxC2, __float_as_uint(s));
    }
}

__global__ void pack_z_kernel(const float* __restrict__ z, _Float16* __restrict__ zf,
                              float* __restrict__ znorm) {
    int tid = threadIdx.x;
    int l = tid & 63, ds = tid >> 6;  // ds 0..3 selects d-subgroup
    int n = blockIdx.x * 64 + l;      // global token
    int b = n >> 8, t = n & 255;
    int kk = ds >> 1, hfb = ds & 1;
    int tb = n >> 7, q = (n >> 5) & 3;
    size_t lanebase = (size_t)tb * 65536 + (size_t)q * 512 +
                      (size_t)((n & 31) + hfb * 32) * 8;
    float zz = 0.f;
    for (int g = 0; g < 16; ++g) {
        int d0 = g * 32 + ds * 8;
        const float* src = z + ((size_t)b * EMBED_DIM + d0) * T_ + t;
        half8 hh;
#pragma unroll
        for (int j = 0; j < 8; ++j) {
            float zo = src[(size_t)j * T_];
            zz += zo * zo;
            hh[j] = (_Float16)(-2.0f * zo);
        }
        int slot = g * 2 + kk;
        *(half8*)(zf + lanebase + (size_t)slot * 2048) = hh;
    }
    atomicAdd(&znorm[n], zz);
}

// ---- pass 1: single-plane f16 argmin GEMM, no LDS staging.
//      4 independent waves/block, each owns 64 codes x 128 tokens; a light
//      barrier every 2 half-steps keeps the 4 waves' shared-B windows
//      L1-resident (B fetched ~once per CU instead of once per wave). ----
#define MFMA16(a, b, c) __builtin_amdgcn_mfma_f32_32x32x16_f16(a, b, c, 0, 0, 0)

#define LDSET(s, hs)                                                  \
    fr[s][0] = *(const half8*)(Ab0 + (hs) * 512 + l8);                \
    fr[s][1] = *(const half8*)(Ab1 + (hs) * 512 + l8);                \
    fr[s][2] = *(const half8*)(Bb + (hs) * 2048 + 0 * 512 + l8);      \
    fr[s][3] = *(const half8*)(Bb + (hs) * 2048 + 1 * 512 + l8);      \
    fr[s][4] = *(const half8*)(Bb + (hs) * 2048 + 2 * 512 + l8);      \
    fr[s][5] = *(const half8*)(Bb + (hs) * 2048 + 3 * 512 + l8);

__global__ __launch_bounds__(256, 2) void argmin_kernel(
    const _Float16* __restrict__ cb_h, const _Float16* __restrict__ zt_h,
    const float* __restrict__ cnorm, u64* __restrict__ slot_m1,
    _Float16* __restrict__ slot_d) {
    const int tid = threadIdx.x;
    const int l = tid & 63;
    const int wv = tid >> 6;  // 0..3
    const int l31 = l & 31;
    const int hf = l >> 5;
    const int cid = blockIdx.y * 4 + wv;  // 64-code chunk id (0..127)
    const _Float16* Ab0 = cb_h + (size_t)(cid * 2) * 16384;
    const _Float16* Ab1 = Ab0 + 16384;
    const _Float16* Bb = zt_h + (size_t)blockIdx.x * 65536;
    const int l8 = l * 8;

    floatx16 acc[2][4];
#pragma unroll
    for (int a = 0; a < 2; ++a)
#pragma unroll
        for (int q = 0; q < 4; ++q)
#pragma unroll
            for (int r = 0; r < 16; ++r) acc[a][q][r] = 0.f;

    half8 fr[3][6];
    LDSET(0, 0)
    LDSET(1, 1)
#pragma unroll
    for (int t = 0; t < 32; ++t) {
        const int s = t % 3;
        if ((t & 1) == 0) __syncthreads();  // keep waves' B windows L1-shared
        if (t + 2 < 32) {
            LDSET((t + 2) % 3, t + 2)
        }
#pragma unroll
        for (int q = 0; q < 4; ++q) acc[0][q] = MFMA16(fr[s][0], fr[s][2 + q], acc[0][q]);
#pragma unroll
        for (int q = 0; q < 4; ++q) acc[1][q] = MFMA16(fr[s][1], fr[s][2 + q], acc[1][q]);
    }

    // epilogue: per (lane,q) one token; this wave covers 64 codes = its chunk
    const int cb0 = cid * 64;
#pragma unroll
    for (int q = 0; q < 4; ++q) {
        u64 m1k = ~0ULL;
        float m1v = 3.4e38f, m2 = 3.4e38f;
#pragma unroll
        for (int ti = 0; ti < 2; ++ti)
#pragma unroll
            for (int g = 0; g < 4; ++g) {
                const int cb4 = cb0 + ti * 32 + g * 8 + hf * 4;
                float4 cn = *(const float4*)(cnorm + cb4);
                float sv[4] = {cn.x + acc[ti][q][g * 4 + 0], cn.y + acc[ti][q][g * 4 + 1],
                               cn.z + acc[ti][q][g * 4 + 2], cn.w + acc[ti][q][g * 4 + 3]};
#pragma unroll
                for (int r = 0; r < 4; ++r) {
                    u64 key = ((u64)mono(sv[r]) << 32) | (uint32_t)(cb4 + r);
                    if (key < m1k) { m2 = m1v; m1v = sv[r]; m1k = key; }
                    else m2 = fminf(m2, sv[r]);
                }
            }
        u64 ok = __shfl_xor(m1k, 32, 64);
        float ov = __shfl_xor(m1v, 32, 64);
        float om2 = __shfl_xor(m2, 32, 64);
        if (ok < m1k) { m2 = fminf(fminf(m2, om2), m1v); m1v = ov; m1k = ok; }
        else m2 = fminf(fminf(m2, om2), ov);
        if (hf == 0) {
            int tok = blockIdx.x * 128 + q * 32 + l31;
            slot_m1[((size_t)cid << 13) + tok] = m1k;
            slot_d[((size_t)cid << 13) + tok] = (_Float16)(m2 - m1v);
        }
    }
}

// ---- combine: 4 threads/token merge 128 chunk summaries; deterministic-bound
//      gap test; emit (tok,chunk) rescore pairs for flagged tokens ----
__global__ void combine_kernel(const u64* __restrict__ slot_m1, const _Float16* __restrict__ slot_d,
                               const float* __restrict__ znorm, const unsigned int* __restrict__ maxC2,
                               u64* __restrict__ wexact, int* __restrict__ pairs,
                               int* __restrict__ npairs) {
    int tid = threadIdx.x;
    int tok = blockIdx.x * 64 + (tid >> 2);
    int sub = tid & 3;
    u64 g1 = ~0ULL;
    float g1v = 3.4e38f, g2 = 3.4e38f;
    for (int c = sub; c < 128; c += 4) {
        u64 k = slot_m1[((size_t)c << 13) + tok];
        float kv = unmono((uint32_t)(k >> 32));
        float v2 = kv + (float)slot_d[((size_t)c << 13) + tok];
        if (k < g1) { g2 = fminf(g2, g1v); g1 = k; g1v = kv; }
        else g2 = fminf(g2, kv);
        g2 = fminf(g2, v2);
    }
    // xor-butterfly merge across the 4 sub-lanes (all lanes get the result)
#pragma unroll
    for (int m = 1; m < 4; m <<= 1) {
        u64 ok = __shfl_xor(g1, m, 64);
        float ov = __shfl_xor(g1v, m, 64);
        float o2 = __shfl_xor(g2, m, 64);
        if (ok < g1) { g2 = fminf(fminf(g2, o2), g1v); g1 = ok; g1v = ov; }
        else g2 = fminf(fminf(g2, o2), ov);
    }
    // deterministic error bound: B = 2^-9 ||z|| maxC ; THR = 2B + slack
    float maxC = sqrtf(__uint_as_float(*maxC2));
    float thr = sqrtf(znorm[tok]) * maxC * (1.0f / 256.0f) + 0.15f;
    if (g2 - g1v > thr) {
        if (sub == 0) wexact[tok] = g1;
    } else {
        float cutv = g1v + thr;
        for (int c = sub; c < 128; c += 4) {
            u64 k = slot_m1[((size_t)c << 13) + tok];
            if (unmono((uint32_t)(k >> 32)) <= cutv) {
                int i = atomicAdd(npairs, 1);
                if (i < MAXPAIRS) pairs[i] = (tok << 7) | c;
            }
        }
    }
}

// ---- fallback v2: exact fp32 rescore, one wave per (tok,chunk) pair,
//      one lane per code; z staged once per pair into a per-wave LDS strip ----
__global__ void fallback_kernel(const float* __restrict__ z, const float* __restrict__ cb,
                                const float* __restrict__ cnorm,
                                const int* __restrict__ pairs, const int* __restrict__ npairs,
                                u64* __restrict__ wexact) {
    __shared__ float zs[4][512];
    int n = *npairs;
    if (n > MAXPAIRS) n = MAXPAIRS;
    const int l = threadIdx.x & 63, wv = threadIdx.x >> 6;
    int wid = blockIdx.x * 4 + wv;
    const int wstride = gridDim.x * 4;
    for (int pi = wid; pi < n; pi += wstride) {
        int pk = pairs[pi];
        int tok = pk >> 7, cid = pk & 127;
        int b = tok >> 8, t = tok & 255;
        const float* zp = z + (size_t)b * EMBED_DIM * T_ + t;
        float zv[8];
#pragma unroll
        for (int j = 0; j < 8; ++j) zv[j] = zp[(size_t)(l * 8 + j) * T_];
        *(float4*)&zs[wv][l * 8] = make_float4(zv[0], zv[1], zv[2], zv[3]);
        *(float4*)&zs[wv][l * 8 + 4] = make_float4(zv[4], zv[5], zv[6], zv[7]);
        // same-wave produce->consume: compiler inserts lgkmcnt wait, no barrier
        int code = cid * 64 + l;
        const float* cp = cb + (size_t)code * EMBED_DIM;
        float acc = 0.f;
#pragma unroll 4
        for (int d = 0; d < 512; d += 4) {
            float4 cv = *(const float4*)(cp + d);
            float4 zq = *(const float4*)&zs[wv][d];
            acc += cv.x * zq.x + cv.y * zq.y + cv.z * zq.z + cv.w * zq.w;
        }
        float s = cnorm[code] - 2.0f * acc;
        u64 key = ((u64)mono(s) << 32) | (uint32_t)code;
#pragma unroll
        for (int m = 32; m; m >>= 1) {
            u64 ok = __shfl_xor(key, m, 64);
            key = ok < key ? ok : key;
        }
        if (l == 0) atomicMin(&wexact[tok], key);
    }
}

// ---- gather: codebook lookup + sse. Each lane sweeps a CONSECUTIVE d-range
//      of its token's code row (L1 line reused 16x) instead of stride-4. ----
__global__ void gather_kernel(const float* __restrict__ z, const float* __restrict__ cb,
                              const u64* __restrict__ wexact,
                              float* __restrict__ out, int* __restrict__ counts,
                              float* __restrict__ sse_acc) {
    __shared__ unsigned int sIdx[64];
    __shared__ float red[4];
    const int tid = threadIdx.x;
    const int n0 = blockIdx.x * 64;
    const int b = n0 >> 8;
    const int t0 = n0 & 255;
    if (tid < 64) {
        unsigned int idx = (unsigned int)(wexact[n0 + tid] & 0xffffffffULL);
        sIdx[tid] = idx;
        atomicAdd(&counts[idx], 1);
    }
    __syncthreads();
    const int w = tid >> 6;
    const int lane = tid & 63;
    const float* crow = cb + (size_t)sIdx[lane] * EMBED_DIM;
    const size_t base = ((size_t)b * EMBED_DIM) * T_ + (size_t)(t0 + lane);
    float sse = 0.f;
    const int d0 = w * 128;
#pragma unroll 4
    for (int i = 0; i < 128; ++i) {
        int d = d0 + i;
        float v = crow[d];
        size_t o = base + (size_t)d * T_;
        float diff = v - z[o];
        out[o] = v;
        sse += diff * diff;
    }
    for (int m = 32; m; m >>= 1) sse += __shfl_xor(sse, m, 64);
    if (lane == 0) red[w] = sse;
    __syncthreads();
    if (tid == 0) atomicAdd(sse_acc, red[0] + red[1] + red[2] + red[3]);
}

__global__ void finalize_kernel(const int* __restrict__ counts,
                                const float* __restrict__ sse_acc,
                                float* __restrict__ out) {
    __shared__ float red[4];
    const int tid = threadIdx.x;
    float e = 0.f;
    for (int k = tid; k < NUM_EMBEDS; k += 256) {
        float p = (float)counts[k] * (1.0f / (float)N_TOK);
        e += p * logf(p + 1e-10f);
    }
    for (int m = 32; m; m >>= 1) e += __shfl_xor(e, m, 64);
    if ((tid & 63) == 0) red[tid >> 6] = e;
    __syncthreads();
    if (tid == 0) {
        float ent = red[0] + red[1] + red[2] + red[3];
        size_t off = (size_t)B_ * EMBED_DIM * T_;
        out[off + 0] = (ALPHA_ * BETA_) * sse_acc[0] / (float)((size_t)N_TOK * EMBED_DIM);
        out[off + 1] = expf(-ent);
    }
}

extern "C" void kernel_launch(void* const* d_in, const int* in_sizes, int n_in,
                              void* d_out, int out_size, void* d_ws, size_t ws_size,
                              hipStream_t stream) {
    const float* z = (const float*)d_in[0];
    const float* cb = (const float*)d_in[1];
    float* out = (float*)d_out;
    char* ws = (char*)d_ws;
    u64* wexact = (u64*)ws;
    float* cnorm = (float*)(ws + 65536);
    int* counts = (int*)(ws + 98304);
    float* znorm = (float*)(ws + 131072);
    float* sse = (float*)(ws + 163840);
    int* npairs = (int*)(ws + 163844);
    unsigned int* maxC2 = (unsigned int*)(ws + 163848);
    u64* slot_m1 = (u64*)(ws + (1ull << 20));
    _Float16* slot_d = (_Float16*)(ws + (9ull << 20));
    _Float16* cb_h = (_Float16*)(ws + (10ull << 20));
    _Float16* zt_h = (_Float16*)(ws + (18ull << 20));
    int* pairs = (int*)(ws + (26ull << 20));

    hipMemsetAsync(wexact, 0xFF, NUM_EMBEDS * sizeof(u64), stream);
    // counts (32K) + znorm (32K) + sse + npairs + maxC2
    hipMemsetAsync(counts, 0, 65536 + 12, stream);

    pack_cb_kernel<<<NUM_EMBEDS / 4, 256, 0, stream>>>(cb, cb_h, cnorm, maxC2);
    pack_z_kernel<<<N_TOK / 64, 256, 0, stream>>>(z, zt_h, znorm);
    argmin_kernel<<<dim3(N_TOK / 128, 32), 256, 0, stream>>>(cb_h, zt_h, cnorm, slot_m1, slot_d);
    combine_kernel<<<N_TOK / 64, 256, 0, stream>>>(slot_m1, slot_d, znorm, maxC2, wexact, pairs, npairs);
    fallback_kernel<<<512, 256, 0, stream>>>(z, cb, cnorm, pairs, npairs, wexact);
    gather_kernel<<<N_TOK / 64, 256, 0, stream>>>(z, cb, wexact, out, counts, sse);
    finalize_kernel<<<1, 256, 0, stream>>>(counts, sse, out);
}

// Round 6
// 426.291 us; speedup vs baseline: 1.3138x; 1.0344x over previous
//
#include <hip/hip_runtime.h>
#include <stdint.h>

typedef _Float16 half8 __attribute__((ext_vector_type(8)));
typedef float floatx16 __attribute__((ext_vector_type(16)));
typedef unsigned long long u64;

#define ALPHA_ 1.0f
#define BETA_ 0.25f
#define NUM_EMBEDS 8192
#define EMBED_DIM 512
#define B_ 32
#define T_ 256
#define N_TOK 8192
#define MAXPAIRS (1 << 20)

// ---------------- ws layout (bytes) ----------------
// wexact   @ 0        (64 KB)  u64 packed exact min: monokey<<32 | code
// cnorm    @ 65536    (32 KB)  ||c||^2 (fp32 exact)
// counts   @ 98304    (32 KB)
// znorm    @ 131072   (32 KB)  ||z_tok||^2 (fp32)
// sse      @ 163840   (4 B)
// npairs   @ 163844   (4 B)
// maxC2    @ 163848   (4 B)   uint bits of max ||c||^2
// slot_m1  @ 1  MB    (8 MB)  u64 [128 chunks][8192 tok] chunk min1 key
// slot_d   @ 9  MB    (2 MB)  f16 [128][8192] (min2 - min1) delta
// cb_h     @ 10 MB    (8 MB)  f16 fragment-major codebook (single plane)
// zt_h     @ 18 MB    (8 MB)  f16 fragment-major -2*z^T (single plane)
// pairs    @ 26 MB    (4 MB)  int (tok<<7)|cid rescore worklist
// ---------------------------------------------------
// fragment-major (halves):
//   cb_h: [ctile32][slot(32)][lane(64)][8]          ctile stride 16384
//   zt_h: [tb128][slot(32)][q(4)][lane(64)][8]      tb stride 65536
// Single-plane numerics: |err(dot)| <= 2^-9 ||z|| maxC. Gap test THR = 2B +
// slack; flagged tokens exactly rescored over chunks with chunkmin <= g1+THR
// (provably sufficient: the true-argmin chunk always qualifies).

__device__ __forceinline__ uint32_t mono(float s) {
    uint32_t u = __float_as_uint(s);
    return (u & 0x80000000u) ? ~u : (u | 0x80000000u);
}
__device__ __forceinline__ float unmono(uint32_t v) {
    return __uint_as_float((v & 0x80000000u) ? (v ^ 0x80000000u) : ~v);
}

__global__ void pack_cb_kernel(const float* __restrict__ cb, _Float16* __restrict__ cf,
                               float* __restrict__ cnorm, unsigned int* __restrict__ maxC2) {
    int row = blockIdx.x * 4 + (threadIdx.x >> 6);
    int l = threadIdx.x & 63;
    const float* src = cb + (size_t)row * EMBED_DIM + l * 8;
    float4 v0 = *(const float4*)src;
    float4 v1 = *(const float4*)(src + 4);
    float x[8] = {v0.x, v0.y, v0.z, v0.w, v1.x, v1.y, v1.z, v1.w};
    half8 hh;
    float s = 0.f;
#pragma unroll
    for (int j = 0; j < 8; ++j) {
        s += x[j] * x[j];
        hh[j] = (_Float16)x[j];
    }
    // lane l covers d in [8l, 8l+8): slot = (l>>2)*2 + ((l>>1)&1), half = l&1
    int slot = (l >> 2) * 2 + ((l >> 1) & 1);
    int flane = (row & 31) + (l & 1) * 32;
    *(half8*)(cf + (size_t)(row >> 5) * 16384 + (size_t)slot * 512 + flane * 8) = hh;
#pragma unroll
    for (int d = 32; d; d >>= 1) s += __shfl_xor(s, d, 64);
    if (l == 0) {
        cnorm[row] = s;
        atomicMax(maxC2, __float_as_uint(s));
    }
}

// 4 y-blocks each handle 4 of the 16 d-groups -> 4x the waves in flight
__global__ void pack_z_kernel(const float* __restrict__ z, _Float16* __restrict__ zf,
                              float* __restrict__ znorm) {
    int tid = threadIdx.x;
    int l = tid & 63, ds = tid >> 6;  // ds 0..3 selects d-subgroup
    int n = blockIdx.x * 64 + l;      // global token
    int b = n >> 8, t = n & 255;
    int kk = ds >> 1, hfb = ds & 1;
    int tb = n >> 7, q = (n >> 5) & 3;
    size_t lanebase = (size_t)tb * 65536 + (size_t)q * 512 +
                      (size_t)((n & 31) + hfb * 32) * 8;
    float zz = 0.f;
    const int g0 = blockIdx.y * 4;
    for (int g = g0; g < g0 + 4; ++g) {
        int d0 = g * 32 + ds * 8;
        const float* src = z + ((size_t)b * EMBED_DIM + d0) * T_ + t;
        half8 hh;
#pragma unroll
        for (int j = 0; j < 8; ++j) {
            float zo = src[(size_t)j * T_];
            zz += zo * zo;
            hh[j] = (_Float16)(-2.0f * zo);
        }
        int slot = g * 2 + kk;
        *(half8*)(zf + lanebase + (size_t)slot * 2048) = hh;
    }
    atomicAdd(&znorm[n], zz);
}

// ---- pass 1: single-plane f16 argmin GEMM, no LDS staging.
//      4 independent waves/block, each owns 64 codes x 128 tokens; a light
//      barrier every 2 half-steps keeps the 4 waves' shared-B windows
//      L1-resident (B fetched ~once per CU instead of once per wave). ----
#define MFMA16(a, b, c) __builtin_amdgcn_mfma_f32_32x32x16_f16(a, b, c, 0, 0, 0)

#define LDSET(s, hs)                                                  \
    fr[s][0] = *(const half8*)(Ab0 + (hs) * 512 + l8);                \
    fr[s][1] = *(const half8*)(Ab1 + (hs) * 512 + l8);                \
    fr[s][2] = *(const half8*)(Bb + (hs) * 2048 + 0 * 512 + l8);      \
    fr[s][3] = *(const half8*)(Bb + (hs) * 2048 + 1 * 512 + l8);      \
    fr[s][4] = *(const half8*)(Bb + (hs) * 2048 + 2 * 512 + l8);      \
    fr[s][5] = *(const half8*)(Bb + (hs) * 2048 + 3 * 512 + l8);

__global__ __launch_bounds__(256, 2) void argmin_kernel(
    const _Float16* __restrict__ cb_h, const _Float16* __restrict__ zt_h,
    const float* __restrict__ cnorm, u64* __restrict__ slot_m1,
    _Float16* __restrict__ slot_d) {
    const int tid = threadIdx.x;
    const int l = tid & 63;
    const int wv = tid >> 6;  // 0..3
    const int l31 = l & 31;
    const int hf = l >> 5;
    const int cid = blockIdx.y * 4 + wv;  // 64-code chunk id (0..127)
    const _Float16* Ab0 = cb_h + (size_t)(cid * 2) * 16384;
    const _Float16* Ab1 = Ab0 + 16384;
    const _Float16* Bb = zt_h + (size_t)blockIdx.x * 65536;
    const int l8 = l * 8;

    floatx16 acc[2][4];
#pragma unroll
    for (int a = 0; a < 2; ++a)
#pragma unroll
        for (int q = 0; q < 4; ++q)
#pragma unroll
            for (int r = 0; r < 16; ++r) acc[a][q][r] = 0.f;

    half8 fr[3][6];
    LDSET(0, 0)
    LDSET(1, 1)
#pragma unroll
    for (int t = 0; t < 32; ++t) {
        const int s = t % 3;
        if ((t & 1) == 0) __syncthreads();  // keep waves' B windows L1-shared
        if (t + 2 < 32) {
            LDSET((t + 2) % 3, t + 2)
        }
#pragma unroll
        for (int q = 0; q < 4; ++q) acc[0][q] = MFMA16(fr[s][0], fr[s][2 + q], acc[0][q]);
#pragma unroll
        for (int q = 0; q < 4; ++q) acc[1][q] = MFMA16(fr[s][1], fr[s][2 + q], acc[1][q]);
    }

    // epilogue: per (lane,q) one token; this wave covers 64 codes = its chunk
    const int cb0 = cid * 64;
#pragma unroll
    for (int q = 0; q < 4; ++q) {
        u64 m1k = ~0ULL;
        float m1v = 3.4e38f, m2 = 3.4e38f;
#pragma unroll
        for (int ti = 0; ti < 2; ++ti)
#pragma unroll
            for (int g = 0; g < 4; ++g) {
                const int cb4 = cb0 + ti * 32 + g * 8 + hf * 4;
                float4 cn = *(const float4*)(cnorm + cb4);
                float sv[4] = {cn.x + acc[ti][q][g * 4 + 0], cn.y + acc[ti][q][g * 4 + 1],
                               cn.z + acc[ti][q][g * 4 + 2], cn.w + acc[ti][q][g * 4 + 3]};
#pragma unroll
                for (int r = 0; r < 4; ++r) {
                    u64 key = ((u64)mono(sv[r]) << 32) | (uint32_t)(cb4 + r);
                    if (key < m1k) { m2 = m1v; m1v = sv[r]; m1k = key; }
                    else m2 = fminf(m2, sv[r]);
                }
            }
        u64 ok = __shfl_xor(m1k, 32, 64);
        float ov = __shfl_xor(m1v, 32, 64);
        float om2 = __shfl_xor(m2, 32, 64);
        if (ok < m1k) { m2 = fminf(fminf(m2, om2), m1v); m1v = ov; m1k = ok; }
        else m2 = fminf(fminf(m2, om2), ov);
        if (hf == 0) {
            int tok = blockIdx.x * 128 + q * 32 + l31;
            slot_m1[((size_t)cid << 13) + tok] = m1k;
            slot_d[((size_t)cid << 13) + tok] = (_Float16)(m2 - m1v);
        }
    }
}

// ---- combine: 16 threads/token merge 128 chunk summaries (512 blocks);
//      deterministic-bound gap test; emit (tok,chunk) rescore pairs ----
__global__ void combine_kernel(const u64* __restrict__ slot_m1, const _Float16* __restrict__ slot_d,
                               const float* __restrict__ znorm, const unsigned int* __restrict__ maxC2,
                               u64* __restrict__ wexact, int* __restrict__ pairs,
                               int* __restrict__ npairs) {
    int tid = threadIdx.x;
    int tok = blockIdx.x * 16 + (tid >> 4);
    int sub = tid & 15;
    u64 g1 = ~0ULL;
    float g1v = 3.4e38f, g2 = 3.4e38f;
    for (int c = sub; c < 128; c += 16) {
        u64 k = slot_m1[((size_t)c << 13) + tok];
        float kv = unmono((uint32_t)(k >> 32));
        float v2 = kv + (float)slot_d[((size_t)c << 13) + tok];
        if (k < g1) { g2 = fminf(g2, g1v); g1 = k; g1v = kv; }
        else g2 = fminf(g2, kv);
        g2 = fminf(g2, v2);
    }
    // xor-butterfly merge across the 16 sub-lanes (all lanes get the result)
#pragma unroll
    for (int m = 1; m < 16; m <<= 1) {
        u64 ok = __shfl_xor(g1, m, 64);
        float ov = __shfl_xor(g1v, m, 64);
        float o2 = __shfl_xor(g2, m, 64);
        if (ok < g1) { g2 = fminf(fminf(g2, o2), g1v); g1 = ok; g1v = ov; }
        else g2 = fminf(fminf(g2, o2), ov);
    }
    // deterministic error bound: B = 2^-9 ||z|| maxC ; THR = 2B + slack
    float maxC = sqrtf(__uint_as_float(*maxC2));
    float thr = sqrtf(znorm[tok]) * maxC * (1.0f / 256.0f) + 0.15f;
    if (g2 - g1v > thr) {
        if (sub == 0) wexact[tok] = g1;
    } else {
        float cutv = g1v + thr;
        for (int c = sub; c < 128; c += 16) {
            u64 k = slot_m1[((size_t)c << 13) + tok];
            if (unmono((uint32_t)(k >> 32)) <= cutv) {
                int i = atomicAdd(npairs, 1);
                if (i < MAXPAIRS) pairs[i] = (tok << 7) | c;
            }
        }
    }
}

// ---- fallback v2: exact fp32 rescore, one wave per (tok,chunk) pair,
//      one lane per code; z staged once per pair into a per-wave LDS strip ----
__global__ void fallback_kernel(const float* __restrict__ z, const float* __restrict__ cb,
                                const float* __restrict__ cnorm,
                                const int* __restrict__ pairs, const int* __restrict__ npairs,
                                u64* __restrict__ wexact) {
    __shared__ float zs[4][512];
    int n = *npairs;
    if (n > MAXPAIRS) n = MAXPAIRS;
    const int l = threadIdx.x & 63, wv = threadIdx.x >> 6;
    int wid = blockIdx.x * 4 + wv;
    const int wstride = gridDim.x * 4;
    for (int pi = wid; pi < n; pi += wstride) {
        int pk = pairs[pi];
        int tok = pk >> 7, cid = pk & 127;
        int b = tok >> 8, t = tok & 255;
        const float* zp = z + (size_t)b * EMBED_DIM * T_ + t;
        float zv[8];
#pragma unroll
        for (int j = 0; j < 8; ++j) zv[j] = zp[(size_t)(l * 8 + j) * T_];
        *(float4*)&zs[wv][l * 8] = make_float4(zv[0], zv[1], zv[2], zv[3]);
        *(float4*)&zs[wv][l * 8 + 4] = make_float4(zv[4], zv[5], zv[6], zv[7]);
        // same-wave produce->consume: compiler inserts lgkmcnt wait, no barrier
        int code = cid * 64 + l;
        const float* cp = cb + (size_t)code * EMBED_DIM;
        float acc = 0.f;
#pragma unroll 4
        for (int d = 0; d < 512; d += 4) {
            float4 cv = *(const float4*)(cp + d);
            float4 zq = *(const float4*)&zs[wv][d];
            acc += cv.x * zq.x + cv.y * zq.y + cv.z * zq.z + cv.w * zq.w;
        }
        float s = cnorm[code] - 2.0f * acc;
        u64 key = ((u64)mono(s) << 32) | (uint32_t)code;
#pragma unroll
        for (int m = 32; m; m >>= 1) {
            u64 ok = __shfl_xor(key, m, 64);
            key = ok < key ? ok : key;
        }
        if (l == 0) atomicMin(&wexact[tok], key);
    }
}

// ---- gather: 32 tokens/block x 512 threads; lane = token, 16 d-groups of 32
//      consecutive d per lane -> 8 waves/CU and 4x shorter latency chain ----
__global__ void gather_kernel(const float* __restrict__ z, const float* __restrict__ cb,
                              const u64* __restrict__ wexact,
                              float* __restrict__ out, int* __restrict__ counts,
                              float* __restrict__ sse_acc) {
    __shared__ unsigned int sIdx[32];
    __shared__ float red[16];
    const int tid = threadIdx.x;
    const int n0 = blockIdx.x * 32;
    const int b = n0 >> 8;
    const int t0 = n0 & 255;
    if (tid < 32) {
        unsigned int idx = (unsigned int)(wexact[n0 + tid] & 0xffffffffULL);
        sIdx[tid] = idx;
        atomicAdd(&counts[idx], 1);
    }
    __syncthreads();
    const int sg = tid >> 5;    // 0..15 d-group
    const int l32 = tid & 31;   // token within block
    const float* crow = cb + (size_t)sIdx[l32] * EMBED_DIM;
    const size_t base = ((size_t)b * EMBED_DIM) * T_ + (size_t)(t0 + l32);
    float sse = 0.f;
    const int d0 = sg * 32;
#pragma unroll 8
    for (int i = 0; i < 32; ++i) {
        int d = d0 + i;
        float v = crow[d];
        size_t o = base + (size_t)d * T_;
        float diff = v - z[o];
        out[o] = v;
        sse += diff * diff;
    }
#pragma unroll
    for (int m = 16; m; m >>= 1) sse += __shfl_xor(sse, m, 64);
    if (l32 == 0) red[sg] = sse;
    __syncthreads();
    if (tid == 0) {
        float s = 0.f;
#pragma unroll
        for (int i = 0; i < 16; ++i) s += red[i];
        atomicAdd(sse_acc, s);
    }
}

__global__ void finalize_kernel(const int* __restrict__ counts,
                                const float* __restrict__ sse_acc,
                                float* __restrict__ out) {
    __shared__ float red[4];
    const int tid = threadIdx.x;
    float e = 0.f;
    for (int k = tid; k < NUM_EMBEDS; k += 256) {
        float p = (float)counts[k] * (1.0f / (float)N_TOK);
        e += p * logf(p + 1e-10f);
    }
    for (int m = 32; m; m >>= 1) e += __shfl_xor(e, m, 64);
    if ((tid & 63) == 0) red[tid >> 6] = e;
    __syncthreads();
    if (tid == 0) {
        float ent = red[0] + red[1] + red[2] + red[3];
        size_t off = (size_t)B_ * EMBED_DIM * T_;
        out[off + 0] = (ALPHA_ * BETA_) * sse_acc[0] / (float)((size_t)N_TOK * EMBED_DIM);
        out[off + 1] = expf(-ent);
    }
}

extern "C" void kernel_launch(void* const* d_in, const int* in_sizes, int n_in,
                              void* d_out, int out_size, void* d_ws, size_t ws_size,
                              hipStream_t stream) {
    const float* z = (const float*)d_in[0];
    const float* cb = (const float*)d_in[1];
    float* out = (float*)d_out;
    char* ws = (char*)d_ws;
    u64* wexact = (u64*)ws;
    float* cnorm = (float*)(ws + 65536);
    int* counts = (int*)(ws + 98304);
    float* znorm = (float*)(ws + 131072);
    float* sse = (float*)(ws + 163840);
    int* npairs = (int*)(ws + 163844);
    unsigned int* maxC2 = (unsigned int*)(ws + 163848);
    u64* slot_m1 = (u64*)(ws + (1ull << 20));
    _Float16* slot_d = (_Float16*)(ws + (9ull << 20));
    _Float16* cb_h = (_Float16*)(ws + (10ull << 20));
    _Float16* zt_h = (_Float16*)(ws + (18ull << 20));
    int* pairs = (int*)(ws + (26ull << 20));

    hipMemsetAsync(wexact, 0xFF, NUM_EMBEDS * sizeof(u64), stream);
    // counts (32K) + znorm (32K) + sse + npairs + maxC2
    hipMemsetAsync(counts, 0, 65536 + 12, stream);

    pack_cb_kernel<<<NUM_EMBEDS / 4, 256, 0, stream>>>(cb, cb_h, cnorm, maxC2);
    pack_z_kernel<<<dim3(N_TOK / 64, 4), 256, 0, stream>>>(z, zt_h, znorm);
    argmin_kernel<<<dim3(N_TOK / 128, 32), 256, 0, stream>>>(cb_h, zt_h, cnorm, slot_m1, slot_d);
    combine_kernel<<<N_TOK / 16, 256, 0, stream>>>(slot_m1, slot_d, znorm, maxC2, wexact, pairs, npairs);
    fallback_kernel<<<512, 256, 0, stream>>>(z, cb, cnorm, pairs, npairs, wexact);
    gather_kernel<<<N_TOK / 32, 512, 0, stream>>>(z, cb, wexact, out, counts, sse);
    finalize_kernel<<<1, 256, 0, stream>>>(counts, sse, out);
}